// Round 7
// baseline (174.775 us; speedup 1.0000x reference)
//
#include <hip/hip_runtime.h>
#include <hip/hip_bf16.h>
#include <math.h>

// ---------------------------------------------------------------------------
// CgpHmmCell forward: 512 seqs x 2048 steps x 25-state HMM (23 live states).
//
// ROUND-23 = 4-BASIS PACKING (v4f over bases, 8 lanes/chunk, 8 chunks/wave).
// Ledger (total cyc/CU): R12 DS=147K(90%)+VALU=85K(52%) wall=163K (OVERLAPS);
// R20/R22 DS=74K+VALU=74K wall=170-183K (NO overlap, cause not visible in
// counters; TLP and prefetch depth both falsified as fixes). Strategy: stop
// fighting the overlap anomaly — shrink the SERIAL sum below R12's wall.
// 4 bases/lane quarters DS: 6 ds_read_b128/wave-step serve 4 chunk-steps.
// DS total 36.9K + VALU ~74-80K = ~111-117K serial floor ~46-49us, beating
// 67.9 even with zero overlap. Numerics: same per-basis expression trees,
// renorm-16 cadence, bf16 stash, 32-chunk combine (R22-validated, absmax 0.0);
// only lane<->basis packing changes.
//
// HARD RULES: never pass __launch_bounds__ min-waves (R4/R14); keep distance-1
// token prefetch (R6); never trade 1 LDS inst for >1 VALU inst (R8/R13);
// renorm-16 with x16 prescale (R11); emission fetch stays on the DS pipe
// (R17/R18 VMEM, R19 SMEM serialize); overlap cannot be restored by TLP (R22)
// or prefetch depth (R21) — shrink the serial sum instead.
// ---------------------------------------------------------------------------

typedef float v4f __attribute__((ext_vector_type(4)));

#define NSTATES 25
#define NLIVE   23
#define NFLAT   216
#define NPACK   100
#define PITCH   28
#define TLEN    2048
#define NSEQ    512
#define CHUNKS  32
#define CLEN    64

#define LOG16 2.772588722239781f

// pos -> canonical state (pad slot = 23, dead)
__device__ __constant__ int PERMC[24] = {1,4,2,5,3,6,7,10,8,11,9,12,
                                         14,17,15,18,16,19,20,0,21,13,22,23};
// canonical state -> position (live states only)
__device__ __constant__ int POSA[NLIVE] = {19,0,2,4,1,3,5,6,8,10,7,9,11,21,
                                           12,14,16,13,15,17,18,20,22};

// ---------------------------------------------------------------------------
// Compile-time emission map (validated: absmax 0.0 across rounds).
// ---------------------------------------------------------------------------
struct WMap { short m[NSTATES * NFLAT]; };

constexpr WMap make_wmap() {
  WMap w{};
  for (int i = 0; i < NSTATES * NFLAT; i++) w.m[i] = -2;
  const unsigned char ST[29] = {0,1,2,3,4,5,6,7,8,9,10,11,11,12,12,12,13,
                                14,15,16,17,18,19,20,21,22,23,23,24};
  const unsigned char M1[29] = {0x1F,0x1F,0x1F,0x11,0x18,0x14,0x1F,0x1F,0x1F,
                                0x1F,0x0F,0x0F,0x0F,0x08,0x08,0x08,0x0F,
                                0x1F,0x1F,0x1F,0x1F,0x1F,0x1F,0x1F,0x1F,0x1F,
                                0x0F,0x0F,0x20};
  const unsigned char M2[29] = {0x1F,0x1F,0x11,0x18,0x14,0x1F,0x1F,0x1F,0x1F,
                                0x1F,0x0F,0x08,0x08,0x01,0x01,0x04,0x0F,
                                0x1F,0x1F,0x1F,0x1F,0x1F,0x1F,0x1F,0x1F,0x1F,
                                0x0F,0x20,0x20};
  const unsigned char M3[29] = {0x0F,0x01,0x08,0x04,0x0F,0x0F,0x0F,0x0F,0x0F,
                                0x0F,0x08,0x01,0x04,0x01,0x04,0x01,0x0F,
                                0x0F,0x0F,0x0F,0x0F,0x0F,0x0F,0x0F,0x0F,0x0F,
                                0x20,0x20,0x20};
  const unsigned char TR[29] = {1,1,1,0,1,1,1,1,1,1,1,1,1,0,0,0,1,
                                1,1,1,1,1,1,1,1,1,1,1,0};
  int k = 0;
  for (int s = 0; s < 29; s++) {
    for (int c1 = 0; c1 < 6; c1++) {
      if (!((M1[s] >> c1) & 1)) continue;
      for (int c2 = 0; c2 < 6; c2++) {
        if (!((M2[s] >> c2) & 1)) continue;
        if (c1 != 4 && c2 == 4) continue;
        for (int c3 = 0; c3 < 6; c3++) {
          if (!((M3[s] >> c3) & 1)) continue;
          w.m[ST[s] * NFLAT + c1 * 36 + c2 * 6 + c3] =
              TR[s] ? (short)(k++) : (short)-1;
        }
      }
    }
  }
  return w;
}
__device__ __constant__ WMap WMAP = make_wmap();

__device__ __forceinline__ unsigned short f2bf(float x) {  // RNE
  unsigned int u = __float_as_uint(x);
  u += 0x7fffu + ((u >> 16) & 1u);
  return (unsigned short)(u >> 16);
}

// weights stay scalar (wave-uniform SGPRs); splats fold into each component op
struct Wp {
  float w0, w1, w2, w3, w4, w5, w6, w7, w8, w9, w10, w11;
  float w13, w14, w15, w16, w17, w18;
};

#define S4(x) ((v4f){(x), (x), (x), (x)})
#define FMA4(a, ws, c) ((v4f){fmaf((a).x, (ws), (c).x), \
                              fmaf((a).y, (ws), (c).y), \
                              fmaf((a).z, (ws), (c).z), \
                              fmaf((a).w, (ws), (c).w)})

// ---------------------------------------------------------------------------
// One HMM step. Q[p] = v4f over 4 bases at PERMUTED position p (p = 0..22;
// pad p23 dropped — identically 0). Exact transcription of the validated
// per-basis expression trees (same mul/add/fmaf shapes) => same values.
// ---------------------------------------------------------------------------
__device__ __forceinline__ void step_pk4(v4f (&Q)[23], const v4f (&F)[6],
                                         const Wp& W) {
  v4f o19 = Q[19], o4 = Q[4], o5 = Q[5], o10 = Q[10], o11 = Q[11];
  v4f o21 = Q[21], o16 = Q[16], o17 = Q[17], o22 = Q[22];
  v4f o18 = Q[18], o20 = Q[20];

  v4f n0  = o19 * S4(W.w0);                    // state0 self
  v4f n1  = o19 * S4(W.w1);                    // 0->1
  v4f n4  = o4 * S4(W.w2)  + o16 * S4(W.w13);  // ->4
  v4f n14 = o4 * S4(W.w3)  + o16 * S4(W.w14);  // ->14
  v4f t77 = o5 * S4(W.w6)  + o17 * S4(W.w15);
  v4f n7  = FMA4(o4, W.w4, t77);               // ->7
  v4f n17 = o5 * S4(W.w7)  + o17 * S4(W.w16);  // ->17
  v4f tAA = o10 * S4(W.w10) + o22 * S4(W.w17);
  v4f n10 = FMA4(o4, W.w5, FMA4(o5, W.w8, tAA));  // ->10
  v4f n20 = o10 * S4(W.w9) + o22 * S4(W.w18);  // ->20
  v4f n13 = FMA4(o21, W.w11, o11);             // ->13

  // shift pairs (transition weight 1.0) x emission — read olds first
  v4f s2  = Q[0]  * S4(F[0].z),  s3  = Q[1]  * S4(F[0].w);
  v4f s4  = Q[2]  * S4(F[1].x),  s5  = Q[3]  * S4(F[1].y);
  v4f s8  = Q[6]  * S4(F[2].x),  s9  = Q[7]  * S4(F[2].y);
  v4f s10 = Q[8]  * S4(F[2].z),  s11 = Q[9]  * S4(F[2].w);
  v4f s14 = Q[12] * S4(F[3].z),  s15 = Q[13] * S4(F[3].w);
  v4f s16 = Q[14] * S4(F[4].x),  s17 = Q[15] * S4(F[4].y);
  v4f s20 = o18 * S4(F[5].x);    // p20 <- old p18 (state20 -> 21)
  v4f s22 = o20 * S4(F[5].z);    // p22 <- old p20 (state21 -> 22)

  Q[0]  = n1  * S4(F[0].x);
  Q[1]  = n4  * S4(F[0].y);
  Q[6]  = n7  * S4(F[1].z);
  Q[7]  = n10 * S4(F[1].w);
  Q[12] = n14 * S4(F[3].x);
  Q[13] = n17 * S4(F[3].y);
  Q[18] = n20 * S4(F[4].z);
  Q[19] = n0  * S4(F[4].w);
  Q[20] = s20;
  Q[21] = n13 * S4(F[5].y);
  Q[22] = s22;
  Q[2] = s2;  Q[3] = s3;  Q[4] = s4;  Q[5] = s5;
  Q[8] = s8;  Q[9] = s9;  Q[10] = s10; Q[11] = s11;
  Q[14] = s14; Q[15] = s15; Q[16] = s16; Q[17] = s17;
}

// renorm every 16 steps; L = v4f over bases. Same add tree per basis as the
// validated renorm ((even positions) then (odd positions), p23 = 0).
__device__ __forceinline__ void renorm_pk4(v4f (&Q)[23], v4f& L) {
  v4f ax = (((Q[0] + Q[2]) + (Q[4] + Q[6])) +
            ((Q[8] + Q[10]) + (Q[12] + Q[14]))) +
           ((Q[16] + Q[18]) + (Q[20] + Q[22]));
  v4f ay = (((Q[1] + Q[3]) + (Q[5] + Q[7])) +
            ((Q[9] + Q[11]) + (Q[13] + Q[15]))) +
           ((Q[17] + Q[19]) + Q[21]);
  v4f s = ax + ay;
  v4f r;
  #pragma unroll
  for (int h = 0; h < 4; h++) {
    bool ok = s[h] > 0.0f;
    L[h] = ok ? L[h] + __logf(s[h]) : -3.0e38f;
    r[h] = ok ? __fdividef(1.0f, s[h]) : 1.0f;
  }
  #pragma unroll
  for (int k = 0; k < 23; k++) Q[k] *= r;
}

// load fp32 row for NEXT step (6 ds_read_b128, pitch-28), then compute
#define LDROW(F, nt_) { int nt = (nt_); \
  const v4f* er = (const v4f*)(sBt + (((c12 << 2) + nt) * PITCH)); \
  F[0] = er[0]; F[1] = er[1]; F[2] = er[2]; \
  F[3] = er[3]; F[4] = er[4]; F[5] = er[5]; \
  c12 = p2 * 5 + nt; p2 = nt; }
#define LDSTEP(Fn, Fc, nt_) { LDROW(Fn, nt_); step_pk4(Q, Fc, W); }

// ---------------------------------------------------------------------------
// One kernel: block = sequence, 256 thr = 4 waves; chunk = 8-lane group
// (4 bases/lane); 32 chunks x CLEN=64.
// ---------------------------------------------------------------------------
__global__ __launch_bounds__(256)
void hmm_kernel(const float* __restrict__ wT, const float* __restrict__ wE,
                const float* __restrict__ wI, const int* __restrict__ tokens,
                float* __restrict__ out) {
  __shared__ __align__(16) float          sBt[NPACK * PITCH];       // 11200 B
  __shared__ __align__(16) unsigned short sT[CHUNKS * NLIVE * 24];  // 35328 B
  __shared__ float sL[CHUNKS * NLIVE];                              //  2944 B
  __shared__ float sAW[24];
  __shared__ float sI[32];

  const int tid   = threadIdx.x;
  const int seq   = blockIdx.x;
  const int chunk = tid >> 3;          // 0..31 (8-lane groups)
  const int row8  = tid & 7;           // bases row8, row8+8, row8+16, row8+24
  const int* trow = tokens + (size_t)seq * TLEN;

  // ---- per-block setup: fp32 emission rows (x16 prescale), PERMUTED order,
  //      pitch 28. Identical per-state arithmetic to the validated build
  //      (32-lane strided sum + shfl tree) -> bit-identical values.
  {
    const int g32 = tid >> 5, r32 = tid & 31;   // 8 groups of 32 lanes
    for (int st = g32; st < NLIVE; st += 8) {
      const int pos = POSA[st];
      float part = 0.0f;
      for (int c = r32; c < NFLAT; c += 32) {
        short m = WMAP.m[st * NFLAT + c];
        if (m == -1) part += expf(1.0f);
        else if (m >= 0) part += expf(wE[m]);
      }
      #pragma unroll
      for (int m = 1; m < 32; m <<= 1) part += __shfl_xor(part, m, 32);
      float inv = 16.0f / part;
      for (int i = r32; i < NPACK; i += 32) {
        int c12 = i >> 2, nt = i & 3;
        int p1 = c12 / 5, p2v = c12 - 5 * p1;
        int flat = p1 * 36 + p2v * 6 + nt;
        short m = WMAP.m[st * NFLAT + flat];
        float v = 0.0f;
        if (m == -1) v = expf(1.0f);
        else if (m >= 0) v = expf(wE[m]);
        sBt[i * PITCH + pos] = v * inv;
      }
    }
  }
  for (int i = tid; i < NPACK; i += 256) sBt[i * PITCH + 23] = 0.0f;  // pad
  if (tid == 224) {
    // softmax of multi-entry A rows -> 21 packed weights (validated)
    const float w0 = wT[0], w1 = wT[1], w2 = wT[2], w3 = wT[3], w4 = wT[4];
    const float w5 = wT[5], w6 = wT[6], w7 = wT[7], w8 = wT[8], w9 = wT[9];
    { float e0 = expf(1.0f - w0), e1 = expf(w0), is = 1.0f / (e0 + e1);
      sAW[0] = e0 * is; sAW[1] = e1 * is; }
    { float e4 = expf(w1), e14 = expf(w3);
      float e7 = expf(1.0f - w9 * w9), e10 = expf(1.0f - w9 * w9 * w9);
      float is = 1.0f / (e4 + e14 + e7 + e10);
      sAW[2] = e4 * is;  sAW[3] = e14 * is;
      sAW[4] = e7 * is;  sAW[5] = e10 * is; }
    { float e7 = expf(w2), e17 = expf(w4), e10 = expf(1.0f - w9 * w9);
      float is = 1.0f / (e7 + e17 + e10);
      sAW[6] = e7 * is; sAW[7] = e17 * is; sAW[8] = e10 * is; }
    { float e20 = expf(w5), e10 = expf(1.0f - w5), is = 1.0f / (e20 + e10);
      sAW[9] = e20 * is; sAW[10] = e10 * is; }
    sAW[11] = 0.5f; sAW[12] = 0.5f;   // row 13
    { float e4 = expf(w6), e14 = expf(1.0f - w6), is = 1.0f / (e4 + e14);
      sAW[13] = e4 * is; sAW[14] = e14 * is; }
    { float e7 = expf(w7), e17 = expf(1.0f - w7), is = 1.0f / (e7 + e17);
      sAW[15] = e7 * is; sAW[16] = e17 * is; }
    { float e10 = expf(w8), e20 = expf(1.0f - w8), is = 1.0f / (e10 + e20);
      sAW[17] = e10 * is; sAW[18] = e20 * is; }
    sAW[19] = 0.5f; sAW[20] = 0.5f;
  } else if (tid == 225) {
    float e[9], s = 0.0f;
    for (int i = 0; i < 9; i++) { e[i] = expf(wI[i]); s += e[i]; }
    float inv = 1.0f / s;
    for (int i = 0; i < 9; i++) sI[i] = e[i] * inv;
    for (int i = 9; i < 32; i++) sI[i] = 0.0f;
  }
  __syncthreads();

  // A-weights: wave-uniform -> SGPRs (scalar; splats fold into VALU ops)
  float w[21];
  #pragma unroll
  for (int i = 0; i < 21; i++)
    w[i] = __uint_as_float(
        (unsigned)__builtin_amdgcn_readfirstlane(__float_as_uint(sAW[i])));
  Wp W;
  W.w0 = w[0];   W.w1 = w[1];   W.w2 = w[2];   W.w3 = w[3];
  W.w4 = w[4];   W.w5 = w[5];   W.w6 = w[6];   W.w7 = w[7];
  W.w8 = w[8];   W.w9 = w[9];   W.w10 = w[10]; W.w11 = w[11];
  W.w13 = w[13]; W.w14 = w[14]; W.w15 = w[15]; W.w16 = w[16];
  W.w17 = w[17]; W.w18 = w[18];

  // ---- scan ----
  const int t0 = chunk * CLEN;

  v4f Q[23];
  #pragma unroll
  for (int p = 0; p < 23; p++) {
    Q[p] = (v4f){ (row8      == PERMC[p]) ? 1.0f : 0.0f,
                  (row8 + 8  == PERMC[p]) ? 1.0f : 0.0f,
                  (row8 + 16 == PERMC[p]) ? 1.0f : 0.0f,
                  (row8 + 24 == PERMC[p]) ? 1.0f : 0.0f };
  }
  v4f L = (v4f){0.0f, 0.0f, 0.0f, 0.0f};

  v4f FA[6], FB[6];
  int c12, p2;
  int4 q0 = *(const int4*)(trow + t0);
  int4 q1 = *(const int4*)(trow + t0 + 4);

  int b = 0;
  if (chunk == 0) {
    // body 0 = steps t = 1..7 (t = 0 folded into the combine's init)
    c12 = 20 + q0.x; p2 = q0.x;
    LDROW(FA, q0.y);
    LDSTEP(FB, FA, q0.z);
    LDSTEP(FA, FB, q0.w);
    LDSTEP(FB, FA, q1.x);
    LDSTEP(FA, FB, q1.y);
    LDSTEP(FB, FA, q1.z);
    LDSTEP(FA, FB, q1.w);
    step_pk4(Q, FA, W);
    b = 1;
    q0 = *(const int4*)(trow + 8);
    q1 = *(const int4*)(trow + 12);
  } else {
    int2 pp = *(const int2*)(trow + t0 - 2);
    c12 = pp.x * 5 + pp.y; p2 = pp.y;
  }

  for (; b < CLEN / 8; b++) {
    int4 n0 = q0, n1 = q1;
    if (b + 1 < CLEN / 8) {               // distance-1 global token prefetch
      n0 = *(const int4*)(trow + t0 + (b + 1) * 8);
      n1 = *(const int4*)(trow + t0 + (b + 1) * 8 + 4);
    }
    LDROW(FA, q0.x);
    LDSTEP(FB, FA, q0.y);
    LDSTEP(FA, FB, q0.z);
    LDSTEP(FB, FA, q0.w);
    LDSTEP(FA, FB, q1.x);
    LDSTEP(FB, FA, q1.y);
    LDSTEP(FA, FB, q1.z);
    LDSTEP(FB, FA, q1.w);
    step_pk4(Q, FB, W);
    if (b & 1) renorm_pk4(Q, L);          // every 16 steps (x16 prescale)
    q0 = n0; q1 = n1;
  }

  // undo the x16 prescale exactly: chunk 0 ran 63 steps, others 64
  const float undo = (chunk == 0 ? 63.0f : 64.0f) * LOG16;
  #pragma unroll
  for (int h = 0; h < 4; h++)
    if (L[h] > -1.0e38f) L[h] -= undo;

  // stash chunk matrix rows (bf16, PERMUTED position order) + fp32 L.
  // basis h lives at canonical state row8 + 8h (live if < 23).
  #pragma unroll
  for (int h = 0; h < 4; h++) {
    const int bs = row8 + 8 * h;
    if (bs < 23) {
      const int base = (chunk * NLIVE + bs) * 24;
      #pragma unroll
      for (int k = 0; k < 12; k++) {
        ushort2 p;
        p.x = f2bf(Q[2 * k][h]);
        p.y = (2 * k + 1 < 23) ? f2bf(Q[2 * k + 1][h]) : (unsigned short)0;
        *(ushort2*)&sT[base + 2 * k] = p;
      }
      sL[chunk * NLIVE + bs] = L[h];
    }
  }
  __syncthreads();

  // ---- combine (wave 0): fold 32 chunk matrices; lane j = canonical col ----
  if (tid < 64) {
    const int lane = tid;
    const bool act = (lane < NLIVE);

    int jp = 23;                          // lane's PERMUTED position
    #pragma unroll
    for (int pos = 0; pos < 23; pos++)
      if (PERMC[pos] == lane) jp = pos;

    const int tok0 = trow[0];
    const int idx0 = 96 + tok0;           // packed (4,4,tok0)

    float v = act ? sI[lane] * sBt[idx0 * PITCH + jp] : 0.0f;
    float s = v;
    #pragma unroll
    for (int m = 1; m < 32; m <<= 1) s += __shfl_xor(s, m, 32);
    float ll = __logf(s) - LOG16;         // undo prescale on step 0
    v = act ? v * __fdividef(1.0f, s) : 0.0f;

    for (int c = 0; c < CHUNKS; c++) {
      float Lj  = act ? sL[c * NLIVE + lane] : -3.0e38f;
      float key = (act && v > 0.0f) ? Lj : -3.0e38f;
      float mx = key;
      #pragma unroll
      for (int m = 1; m < 32; m <<= 1) mx = fmaxf(mx, __shfl_xor(mx, m, 32));
      float wgt = (act && v > 0.0f) ? v * __expf(Lj - mx) : 0.0f;

      float nv = 0.0f;
      #pragma unroll
      for (int r = 0; r < NLIVE; r++) {
        float wr = __shfl(wgt, r, 64);
        nv += wr * __uint_as_float(((unsigned)sT[(c * NLIVE + r) * 24 + jp]) << 16);
      }
      float nva = act ? nv : 0.0f;
      float s2 = nva;
      #pragma unroll
      for (int m = 1; m < 32; m <<= 1) s2 += __shfl_xor(s2, m, 32);
      ll += mx + __logf(s2);
      v = act ? nv * __fdividef(1.0f, s2) : 0.0f;
    }

    if (lane == 0) out[seq] = ll;
  }
}

// ---------------------------------------------------------------------------
extern "C" void kernel_launch(void* const* d_in, const int* in_sizes, int n_in,
                              void* d_out, int out_size, void* d_ws, size_t ws_size,
                              hipStream_t stream) {
  const float* wT = (const float*)d_in[0];   // transition_kernel (10)
  const float* wE = (const float*)d_in[1];   // emission_kernel (5400)
  const float* wI = (const float*)d_in[2];   // init_kernel (25)
  const int* tokens = (const int*)d_in[3];   // (512, 2048) int32
  float* out = (float*)d_out;                // (512,) float32
  (void)d_ws; (void)ws_size;                 // workspace unused

  hmm_kernel<<<NSEQ, 256, 0, stream>>>(wT, wE, wI, tokens, out);
}

// Round 8
// 121.194 us; speedup vs baseline: 1.4421x; 1.4421x over previous
//
#include <hip/hip_runtime.h>
#include <hip/hip_bf16.h>
#include <math.h>

// ---------------------------------------------------------------------------
// CgpHmmCell forward: 512 seqs x 2048 steps x 25-state HMM (23 live states).
//
// ROUND-24 = EXACT REVERT TO R12 (best measured: kernel 67.9 us, total
// 120.6 us, absmax 0.0). Session ledger (kernel us): R12=67.9; VMEM split
// R17/R18=82-84; SMEM rows R19=91.5; 2-basis packing R20/R21/R22=70.7-76.4;
// 4-basis packing R23=125.9. R12 is the unique overlap point: DS 90% busy +
// VALU 52% busy (sum 142% => true DS/VALU co-issue); its wall is the per-CU
// LDS pipe servicing 96 broadcast ds_read_b128/step (~1152/1273 cyc), VALU
// fully hidden. Every deviation that cuts DS work (basis packing: conflicts
// halve exactly with DS insts) LOSES the overlap (busy-sum <=87%) by more
// than it saves; VMEM/SMEM fetch serializes per-step; TLP (R22) and prefetch
// depth (R21/R18) change nothing. Structural floor for this decomposition.
//
// HARD RULES (full session): never pass __launch_bounds__ min-waves (R4/R14);
// keep the distance-1 global token prefetch (R6); never trade 1 LDS inst for
// >1 VALU inst (R8/R13); renorm every 16 steps with x16 emission prescale
// (R11, absmax 0.0); emission fetch stays on the DS pipe (R17/R18/R19);
// do not unpack the 32-lane/1-basis layout (R20-R23).
// ---------------------------------------------------------------------------

typedef float v2f __attribute__((ext_vector_type(2)));
typedef float v4f __attribute__((ext_vector_type(4)));

#define NSTATES 25
#define NLIVE   23
#define NFLAT   216
#define NPACK   100
#define TLEN    2048
#define NSEQ    512
#define CHUNKS  16
#define CLEN    128

#define LOG16 2.772588722239781f

// pos -> canonical state (pad slot = 23, dead)
__device__ __constant__ int PERMC[24] = {1,4,2,5,3,6,7,10,8,11,9,12,
                                         14,17,15,18,16,19,20,0,21,13,22,23};
// canonical state -> position (live states only)
__device__ __constant__ int POSA[NLIVE] = {19,0,2,4,1,3,5,6,8,10,7,9,11,21,
                                           12,14,16,13,15,17,18,20,22};

// ---------------------------------------------------------------------------
// Compile-time emission map (validated: absmax 0.0 across rounds).
// ---------------------------------------------------------------------------
struct WMap { short m[NSTATES * NFLAT]; };

constexpr WMap make_wmap() {
  WMap w{};
  for (int i = 0; i < NSTATES * NFLAT; i++) w.m[i] = -2;
  const unsigned char ST[29] = {0,1,2,3,4,5,6,7,8,9,10,11,11,12,12,12,13,
                                14,15,16,17,18,19,20,21,22,23,23,24};
  const unsigned char M1[29] = {0x1F,0x1F,0x1F,0x11,0x18,0x14,0x1F,0x1F,0x1F,
                                0x1F,0x0F,0x0F,0x0F,0x08,0x08,0x08,0x0F,
                                0x1F,0x1F,0x1F,0x1F,0x1F,0x1F,0x1F,0x1F,0x1F,
                                0x0F,0x0F,0x20};
  const unsigned char M2[29] = {0x1F,0x1F,0x11,0x18,0x14,0x1F,0x1F,0x1F,0x1F,
                                0x1F,0x0F,0x08,0x08,0x01,0x01,0x04,0x0F,
                                0x1F,0x1F,0x1F,0x1F,0x1F,0x1F,0x1F,0x1F,0x1F,
                                0x0F,0x20,0x20};
  const unsigned char M3[29] = {0x0F,0x01,0x08,0x04,0x0F,0x0F,0x0F,0x0F,0x0F,
                                0x0F,0x08,0x01,0x04,0x01,0x04,0x01,0x0F,
                                0x0F,0x0F,0x0F,0x0F,0x0F,0x0F,0x0F,0x0F,0x0F,
                                0x20,0x20,0x20};
  const unsigned char TR[29] = {1,1,1,0,1,1,1,1,1,1,1,1,1,0,0,0,1,
                                1,1,1,1,1,1,1,1,1,1,1,0};
  int k = 0;
  for (int s = 0; s < 29; s++) {
    for (int c1 = 0; c1 < 6; c1++) {
      if (!((M1[s] >> c1) & 1)) continue;
      for (int c2 = 0; c2 < 6; c2++) {
        if (!((M2[s] >> c2) & 1)) continue;
        if (c1 != 4 && c2 == 4) continue;
        for (int c3 = 0; c3 < 6; c3++) {
          if (!((M3[s] >> c3) & 1)) continue;
          w.m[ST[s] * NFLAT + c1 * 36 + c2 * 6 + c3] =
              TR[s] ? (short)(k++) : (short)-1;
        }
      }
    }
  }
  return w;
}
__device__ __constant__ WMap WMAP = make_wmap();

__device__ __forceinline__ unsigned short f2bf(float x) {  // RNE
  unsigned int u = __float_as_uint(x);
  u += 0x7fffu + ((u >> 16) & 1u);
  return (unsigned short)(u >> 16);
}

struct Wp {
  v2f w01, wA, wB, wC, wD, wE, wF;
  float w4, w5, w8, w11;
};

// ---------------------------------------------------------------------------
// One HMM step in permuted-pair layout, fp32 emission row in registers
// (F[0..5] = positions 0..23). Validated R12 (absmax 0.0).
// ---------------------------------------------------------------------------
__device__ __forceinline__ void step_pk(v2f (&Q)[12], const v4f (&F)[6],
                                        const Wp& W) {
  float a0 = Q[9].y,  a3 = Q[2].x,  a6 = Q[2].y,  a9 = Q[5].x;
  float a12 = Q[5].y, a13 = Q[10].y, a16 = Q[8].x, a19 = Q[8].y, a22 = Q[11].x;
  float q9x = Q[9].x, q10x = Q[10].x;   // old a20, a21

  v2f t01 = a0 * W.w01;                  // (n0, n1)
  v2f t44 = a3 * W.wA + a16 * W.wB;      // (n4, n14)
  v2f t77 = a6 * W.wC + a19 * W.wD;      // (n7 partial, n17)
  float n7  = fmaf(a3, W.w4, t77.x);
  v2f tAA = a9 * W.wE + a22 * W.wF;      // (n10 partial, n20)
  float n10 = fmaf(a3, W.w5, fmaf(a6, W.w8, tAA.x));
  float n13 = fmaf(a13, W.w11, a12);

  // aligned shift pairs (transition weight 1.0) * emission pair
  v2f nQ1 = Q[0] * __builtin_shufflevector(F[0], F[0], 2, 3);  // (e2,e5)
  v2f nQ2 = Q[1] * __builtin_shufflevector(F[1], F[1], 0, 1);  // (e3,e6)
  v2f nQ4 = Q[3] * __builtin_shufflevector(F[2], F[2], 0, 1);  // (e8,e11)
  v2f nQ5 = Q[4] * __builtin_shufflevector(F[2], F[2], 2, 3);  // (e9,e12)
  v2f nQ7 = Q[6] * __builtin_shufflevector(F[3], F[3], 2, 3);  // (e15,e18)
  v2f nQ8 = Q[7] * __builtin_shufflevector(F[4], F[4], 0, 1);  // (e16,e19)

  Q[0]  = (v2f){ t01.y * F[0].x, t44.x * F[0].y };   // (n1*e1,  n4*e4)
  Q[3]  = (v2f){ n7    * F[1].z, n10   * F[1].w };   // (n7*e7,  n10*e10)
  Q[6]  = (v2f){ t44.y * F[3].x, t77.y * F[3].y };   // (n14*e14, n17*e17)
  Q[9]  = (v2f){ tAA.y * F[4].z, t01.x * F[4].w };   // (n20*e20, n0*e0)
  Q[10] = (v2f){ q9x   * F[5].x, n13   * F[5].y };   // (a20*e21, n13*e13)
  Q[11].x = q10x * F[5].z;                           // a21*e22 (pad .y stays)
  Q[1] = nQ1; Q[2] = nQ2; Q[4] = nQ4; Q[5] = nQ5; Q[7] = nQ7; Q[8] = nQ8;
}

__device__ __forceinline__ void renorm_pk(v2f (&Q)[12], float& L) {
  v2f acc = ((Q[0] + Q[1]) + (Q[2] + Q[3])) + ((Q[4] + Q[5]) + (Q[6] + Q[7]))
          + ((Q[8] + Q[9]) + (Q[10] + Q[11]));
  float s = acc.x + acc.y;
  if (s > 0.0f) {
    L += __logf(s);
    float r = __fdividef(1.0f, s);
    #pragma unroll
    for (int k = 0; k < 12; k++) Q[k] *= r;
  } else {
    L = -3.0e38f;  // row died; stays dead
  }
}

// load fp32 row for NEXT step (6 ds_read_b128), then compute the CURRENT one
#define LDROW(F, nt_) { int nt = (nt_); \
  const v4f* er = (const v4f*)(sBt + (((c12 << 2) + nt) << 5)); \
  F[0] = er[0]; F[1] = er[1]; F[2] = er[2]; \
  F[3] = er[3]; F[4] = er[4]; F[5] = er[5]; \
  c12 = p2 * 5 + nt; p2 = nt; }
#define LDSTEP(Fn, Fc, nt_) { LDROW(Fn, nt_); step_pk(Q, Fc, W); }

// ---------------------------------------------------------------------------
// One kernel: block = sequence, 512 thr = 16 chunks x 32 lanes, CLEN=128.
// ---------------------------------------------------------------------------
__global__ __launch_bounds__(512)
void hmm_kernel(const float* __restrict__ wT, const float* __restrict__ wE,
                const float* __restrict__ wI, const int* __restrict__ tokens,
                float* __restrict__ out) {
  __shared__ __align__(16) float          sBt[NPACK * 32];          // 12800 B
  __shared__ __align__(16) unsigned short sT[CHUNKS * NLIVE * 24];  // 17664 B
  __shared__ float sL[CHUNKS * NLIVE];                              //  1472 B
  __shared__ float sAW[24];
  __shared__ float sI[32];

  const int tid   = threadIdx.x;
  const int seq   = blockIdx.x;
  const int chunk = tid >> 5;
  const int row   = tid & 31;
  const int* trow = tokens + (size_t)seq * TLEN;

  // ---- per-block setup: fp32 emission rows (x16 prescale), PERMUTED order --
  for (int st = chunk; st < NLIVE; st += 16) {
    const int pos = POSA[st];
    float part = 0.0f;
    for (int c = row; c < NFLAT; c += 32) {
      short m = WMAP.m[st * NFLAT + c];
      if (m == -1) part += expf(1.0f);
      else if (m >= 0) part += expf(wE[m]);
    }
    #pragma unroll
    for (int m = 1; m < 32; m <<= 1) part += __shfl_xor(part, m, 32);
    float inv = 16.0f / part;
    for (int i = row; i < NPACK; i += 32) {
      int c12 = i >> 2, nt = i & 3;
      int p1 = c12 / 5, p2v = c12 - 5 * p1;
      int flat = p1 * 36 + p2v * 6 + nt;
      short m = WMAP.m[st * NFLAT + flat];
      float v = 0.0f;
      if (m == -1) v = expf(1.0f);
      else if (m >= 0) v = expf(wE[m]);
      sBt[i * 32 + pos] = v * inv;
    }
  }
  for (int i = tid; i < NPACK; i += 512) sBt[i * 32 + 23] = 0.0f;  // pad slot
  if (tid == 480) {
    // softmax of multi-entry A rows -> 21 packed weights (validated)
    const float w0 = wT[0], w1 = wT[1], w2 = wT[2], w3 = wT[3], w4 = wT[4];
    const float w5 = wT[5], w6 = wT[6], w7 = wT[7], w8 = wT[8], w9 = wT[9];
    { float e0 = expf(1.0f - w0), e1 = expf(w0), is = 1.0f / (e0 + e1);
      sAW[0] = e0 * is; sAW[1] = e1 * is; }
    { float e4 = expf(w1), e14 = expf(w3);
      float e7 = expf(1.0f - w9 * w9), e10 = expf(1.0f - w9 * w9 * w9);
      float is = 1.0f / (e4 + e14 + e7 + e10);
      sAW[2] = e4 * is;  sAW[3] = e14 * is;
      sAW[4] = e7 * is;  sAW[5] = e10 * is; }
    { float e7 = expf(w2), e17 = expf(w4), e10 = expf(1.0f - w9 * w9);
      float is = 1.0f / (e7 + e17 + e10);
      sAW[6] = e7 * is; sAW[7] = e17 * is; sAW[8] = e10 * is; }
    { float e20 = expf(w5), e10 = expf(1.0f - w5), is = 1.0f / (e20 + e10);
      sAW[9] = e20 * is; sAW[10] = e10 * is; }
    sAW[11] = 0.5f; sAW[12] = 0.5f;   // row 13
    { float e4 = expf(w6), e14 = expf(1.0f - w6), is = 1.0f / (e4 + e14);
      sAW[13] = e4 * is; sAW[14] = e14 * is; }
    { float e7 = expf(w7), e17 = expf(1.0f - w7), is = 1.0f / (e7 + e17);
      sAW[15] = e7 * is; sAW[16] = e17 * is; }
    { float e10 = expf(w8), e20 = expf(1.0f - w8), is = 1.0f / (e10 + e20);
      sAW[17] = e10 * is; sAW[18] = e20 * is; }
    sAW[19] = 0.5f; sAW[20] = 0.5f;
  } else if (tid == 481) {
    float e[9], s = 0.0f;
    for (int i = 0; i < 9; i++) { e[i] = expf(wI[i]); s += e[i]; }
    float inv = 1.0f / s;
    for (int i = 0; i < 9; i++) sI[i] = e[i] * inv;
    for (int i = 9; i < 32; i++) sI[i] = 0.0f;
  }
  __syncthreads();

  // A-weights: wave-uniform -> SGPRs, then packed pairs
  float w[21];
  #pragma unroll
  for (int i = 0; i < 21; i++)
    w[i] = __uint_as_float(
        (unsigned)__builtin_amdgcn_readfirstlane(__float_as_uint(sAW[i])));
  Wp W;
  W.w01 = (v2f){w[0],  w[1]};
  W.wA  = (v2f){w[2],  w[3]};
  W.wB  = (v2f){w[13], w[14]};
  W.wC  = (v2f){w[6],  w[7]};
  W.wD  = (v2f){w[15], w[16]};
  W.wE  = (v2f){w[10], w[9]};
  W.wF  = (v2f){w[17], w[18]};
  W.w4 = w[4]; W.w5 = w[5]; W.w8 = w[8]; W.w11 = w[11];

  // ---- scan ----
  const int t0 = chunk * CLEN;

  v2f Q[12];
  #pragma unroll
  for (int k = 0; k < 12; k++) {
    Q[k].x = (row == PERMC[2 * k]) ? 1.0f : 0.0f;
    Q[k].y = (row == PERMC[2 * k + 1]) ? 1.0f : 0.0f;
  }
  float L = 0.0f;

  v4f FA[6], FB[6];
  int c12, p2;
  int4 q0 = *(const int4*)(trow + t0);
  int4 q1 = *(const int4*)(trow + t0 + 4);

  int b = 0;
  if (chunk == 0) {
    // body 0 = steps t = 1..7 (t = 0 folded into the combine's init)
    c12 = 20 + q0.x; p2 = q0.x;
    LDROW(FA, q0.y);
    LDSTEP(FB, FA, q0.z);
    LDSTEP(FA, FB, q0.w);
    LDSTEP(FB, FA, q1.x);
    LDSTEP(FA, FB, q1.y);
    LDSTEP(FB, FA, q1.z);
    LDSTEP(FA, FB, q1.w);
    step_pk(Q, FA, W);
    b = 1;
    q0 = *(const int4*)(trow + 8);
    q1 = *(const int4*)(trow + 12);
  } else {
    int2 pp = *(const int2*)(trow + t0 - 2);
    c12 = pp.x * 5 + pp.y; p2 = pp.y;
  }

  for (; b < CLEN / 8; b++) {
    int4 n0 = q0, n1 = q1;
    if (b + 1 < CLEN / 8) {               // distance-1 global token prefetch
      n0 = *(const int4*)(trow + t0 + (b + 1) * 8);
      n1 = *(const int4*)(trow + t0 + (b + 1) * 8 + 4);
    }
    LDROW(FA, q0.x);
    LDSTEP(FB, FA, q0.y);
    LDSTEP(FA, FB, q0.z);
    LDSTEP(FB, FA, q0.w);
    LDSTEP(FA, FB, q1.x);
    LDSTEP(FB, FA, q1.y);
    LDSTEP(FA, FB, q1.z);
    LDSTEP(FB, FA, q1.w);
    step_pk(Q, FB, W);
    if (b & 1) renorm_pk(Q, L);           // every 16 steps (x16 prescale)
    q0 = n0; q1 = n1;
  }

  // undo the x16 prescale exactly: chunk 0 ran 127 steps, others 128
  if (L > -1.0e38f) L -= (chunk == 0 ? 127.0f : 128.0f) * LOG16;

  // stash chunk matrix row (bf16, PERMUTED position order) + fp32 L
  if (row < NLIVE) {
    const int base = (chunk * NLIVE + row) * 24;
    #pragma unroll
    for (int k = 0; k < 12; k++) {
      ushort2 p; p.x = f2bf(Q[k].x); p.y = f2bf(Q[k].y);
      *(ushort2*)&sT[base + 2 * k] = p;
    }
    sL[chunk * NLIVE + row] = L;
  }
  __syncthreads();

  // ---- combine (wave 0): fold 16 chunk matrices; lane j = canonical col ----
  if (tid < 64) {
    const int lane = tid;
    const bool act = (lane < NLIVE);

    int jp = 23;                          // lane's PERMUTED position
    #pragma unroll
    for (int pos = 0; pos < 23; pos++)
      if (PERMC[pos] == lane) jp = pos;

    const int tok0 = trow[0];
    const int idx0 = 96 + tok0;           // packed (4,4,tok0)

    float v = act ? sI[lane] * sBt[idx0 * 32 + jp] : 0.0f;
    float s = v;
    #pragma unroll
    for (int m = 1; m < 32; m <<= 1) s += __shfl_xor(s, m, 32);
    float ll = __logf(s) - LOG16;         // undo prescale on step 0
    v = act ? v * __fdividef(1.0f, s) : 0.0f;

    for (int c = 0; c < CHUNKS; c++) {
      float Lj  = act ? sL[c * NLIVE + lane] : -3.0e38f;
      float key = (act && v > 0.0f) ? Lj : -3.0e38f;
      float mx = key;
      #pragma unroll
      for (int m = 1; m < 32; m <<= 1) mx = fmaxf(mx, __shfl_xor(mx, m, 32));
      float wgt = (act && v > 0.0f) ? v * __expf(Lj - mx) : 0.0f;

      float nv = 0.0f;
      #pragma unroll
      for (int r = 0; r < NLIVE; r++) {
        float wr = __shfl(wgt, r, 64);
        nv += wr * __uint_as_float(((unsigned)sT[(c * NLIVE + r) * 24 + jp]) << 16);
      }
      float nva = act ? nv : 0.0f;
      float s2 = nva;
      #pragma unroll
      for (int m = 1; m < 32; m <<= 1) s2 += __shfl_xor(s2, m, 32);
      ll += mx + __logf(s2);
      v = act ? nv * __fdividef(1.0f, s2) : 0.0f;
    }

    if (lane == 0) out[seq] = ll;
  }
}

// ---------------------------------------------------------------------------
extern "C" void kernel_launch(void* const* d_in, const int* in_sizes, int n_in,
                              void* d_out, int out_size, void* d_ws, size_t ws_size,
                              hipStream_t stream) {
  const float* wT = (const float*)d_in[0];   // transition_kernel (10)
  const float* wE = (const float*)d_in[1];   // emission_kernel (5400)
  const float* wI = (const float*)d_in[2];   // init_kernel (25)
  const int* tokens = (const int*)d_in[3];   // (512, 2048) int32
  float* out = (float*)d_out;                // (512,) float32
  (void)d_ws; (void)ws_size;                 // workspace unused

  hmm_kernel<<<NSEQ, 512, 0, stream>>>(wT, wE, wI, tokens, out);
}